// Round 9
// baseline (1054.268 us; speedup 1.0000x reference)
//
#include <hip/hip_runtime.h>

typedef __bf16 bf16;
typedef __bf16 bf16x8 __attribute__((ext_vector_type(8)));
typedef float f32x4 __attribute__((ext_vector_type(4)));

#define S_NB 50

// ---------------- weight pre-shuffle: f32 -> bf16 MFMA B-fragment layout ----
__global__ __launch_bounds__(256) void shuffle_w(const float* __restrict__ gatW,
                                                 bf16* __restrict__ ws) {
  int tid = blockIdx.x * 256 + threadIdx.x;
  if (tid >= 6 * 512) return;
  int mat = tid >> 9;
  int rem = tid & 511;
  int ks = rem >> 8;
  int nt = (rem >> 6) & 3;
  int lane = rem & 63;
  int t = mat >> 1, p = (mat & 1) + 1;
  const float* src = gatW + (size_t)(t * 4 + p) * 4096;
  int n = nt * 16 + (lane & 15);
  int kb = ks * 32 + (lane >> 4) * 8;
  bf16x8 v;
#pragma unroll
  for (int e = 0; e < 8; ++e) v[e] = (bf16)src[(kb + e) * 64 + n];
  *reinterpret_cast<bf16x8*>(ws + mat * 4096 + ((ks * 4 + nt) * 64 + lane) * 8) = v;
}

// ---------------- round-5 PROVEN block-wide layers (verbatim) ---------------
struct Smem {
  float qp[64];
  float sc[64];
  float eb[64];
  float yp[4 * 64];
  float y[64];
  float pp[4 * 64];
  float kvp[2 * 3 * 64];
};

__device__ __forceinline__ void proj64(const float* src, const float* W,
                                       const float* bias, float* dst, Smem* sm,
                                       int wave, int lane, int tid) {
  float part = 0.f;
  const float* wp = W + wave * 16 * 64 + lane;
  const float* sp = src + wave * 16;
#pragma unroll
  for (int kk = 0; kk < 16; ++kk) part += sp[kk] * wp[kk * 64];
  sm->pp[wave * 64 + lane] = part;
  __syncthreads();
  if (tid < 64) {
    float v = sm->pp[tid] + sm->pp[64 + tid] + sm->pp[128 + tid] +
              sm->pp[192 + tid] + bias[tid];
    dst[tid] = fmaxf(v, 0.f);
  }
  __syncthreads();
}

__device__ __forceinline__ void gat_layer(
    int b, const int* idx, const float* table, const float* Wt,
    const float* bt, const bf16* frags, const float* node, float* aggdst,
    Smem* sm, int wave, int lane, int tid) {
  int arow = wave * 16 + (lane & 15);
  int id = (arow < S_NB) ? idx[b * S_NB + arow] : 0; // row 0 of tables is zeros
  const float* rowp = table + (size_t)id * 64;
  int g = lane >> 4;
  float4 f0 = *reinterpret_cast<const float4*>(rowp + g * 8);
  float4 f1 = *reinterpret_cast<const float4*>(rowp + g * 8 + 4);
  float4 f2 = *reinterpret_cast<const float4*>(rowp + 32 + g * 8);
  float4 f3 = *reinterpret_cast<const float4*>(rowp + 32 + g * 8 + 4);
  bf16x8 a0, a1;
  a0[0] = (bf16)f0.x; a0[1] = (bf16)f0.y; a0[2] = (bf16)f0.z; a0[3] = (bf16)f0.w;
  a0[4] = (bf16)f1.x; a0[5] = (bf16)f1.y; a0[6] = (bf16)f1.z; a0[7] = (bf16)f1.w;
  a1[0] = (bf16)f2.x; a1[1] = (bf16)f2.y; a1[2] = (bf16)f2.z; a1[3] = (bf16)f2.w;
  a1[4] = (bf16)f3.x; a1[5] = (bf16)f3.y; a1[6] = (bf16)f3.z; a1[7] = (bf16)f3.w;

  // qp = relu(node @ W0 + b0)  (exact f32)
  proj64(node, Wt, bt, sm->qp, sm, wave, lane, tid);

  // kp/vp = relu(NB @ W{1,2} + b{1,2}) via bf16 MFMA; stay in registers (f32).
  f32x4 kacc[4], vacc[4];
#pragma unroll
  for (int nt = 0; nt < 4; ++nt) {
    kacc[nt] = f32x4{0.f, 0.f, 0.f, 0.f};
    vacc[nt] = f32x4{0.f, 0.f, 0.f, 0.f};
  }
  const bf16* fk = frags;
  const bf16* fv = frags + 4096;
#pragma unroll
  for (int nt = 0; nt < 4; ++nt) {
#pragma unroll
    for (int ks = 0; ks < 2; ++ks) {
      bf16x8 a = ks ? a1 : a0;
      bf16x8 bk = *reinterpret_cast<const bf16x8*>(fk + ((ks * 4 + nt) * 64 + lane) * 8);
      kacc[nt] = __builtin_amdgcn_mfma_f32_16x16x32_bf16(a, bk, kacc[nt], 0, 0, 0);
      bf16x8 bv = *reinterpret_cast<const bf16x8*>(fv + ((ks * 4 + nt) * 64 + lane) * 8);
      vacc[nt] = __builtin_amdgcn_mfma_f32_16x16x32_bf16(a, bv, vacc[nt], 0, 0, 0);
    }
  }
  const float* b1 = bt + 64;
  const float* b2 = bt + 128;
#pragma unroll
  for (int nt = 0; nt < 4; ++nt) {
    float kb = b1[nt * 16 + (lane & 15)];
    float vb = b2[nt * 16 + (lane & 15)];
#pragma unroll
    for (int e = 0; e < 4; ++e) {
      kacc[nt][e] = fmaxf(kacc[nt][e] + kb, 0.f);
      vacc[nt][e] = fmaxf(vacc[nt][e] + vb, 0.f);
    }
  }

  // scores[row] = dot(qp, kp[row])
  float s[4] = {0.f, 0.f, 0.f, 0.f};
#pragma unroll
  for (int nt = 0; nt < 4; ++nt) {
    float qv = sm->qp[nt * 16 + (lane & 15)];
#pragma unroll
    for (int e = 0; e < 4; ++e) s[e] += kacc[nt][e] * qv;
  }
#pragma unroll
  for (int m = 1; m < 16; m <<= 1) {
#pragma unroll
    for (int e = 0; e < 4; ++e) s[e] += __shfl_xor(s[e], m, 64);
  }
  int rbase = wave * 16 + (lane >> 4) * 4;
  if ((lane & 15) == 0) {
#pragma unroll
    for (int e = 0; e < 4; ++e) sm->sc[rbase + e] = s[e];
  }
  __syncthreads();

  // softmax over 50 (scale 1/8 folded into exp)
  float mx = -1e30f;
  for (int i = 0; i < S_NB; ++i) mx = fmaxf(mx, sm->sc[i]);
  if (tid < 64) sm->eb[tid] = (tid < S_NB) ? __expf((sm->sc[tid] - mx) * 0.125f) : 0.f;
  __syncthreads();
  float den = 0.f;
  for (int i = 0; i < S_NB; ++i) den += sm->eb[i];
  float rden = 1.f / den;

  // y = sum_s a[s]*vp[s]
  float ew[4];
#pragma unroll
  for (int e = 0; e < 4; ++e) ew[e] = sm->eb[rbase + e];
  float p[4];
#pragma unroll
  for (int nt = 0; nt < 4; ++nt) {
    p[nt] = ew[0] * vacc[nt][0] + ew[1] * vacc[nt][1] + ew[2] * vacc[nt][2] +
            ew[3] * vacc[nt][3];
    p[nt] += __shfl_xor(p[nt], 16, 64);
    p[nt] += __shfl_xor(p[nt], 32, 64);
  }
  if (lane < 16) {
#pragma unroll
    for (int nt = 0; nt < 4; ++nt) sm->yp[wave * 64 + nt * 16 + lane] = p[nt];
  }
  __syncthreads();
  if (tid < 64)
    sm->y[tid] = (sm->yp[tid] + sm->yp[64 + tid] + sm->yp[128 + tid] +
                  sm->yp[192 + tid]) * rden;
  __syncthreads();

  // agg = relu(y @ W3 + b3)
  proj64(sm->y, Wt + 3 * 4096, bt + 192, aggdst, sm, wave, lane, tid);
}

__device__ __forceinline__ void sem_layer(int ns, const float* node,
                                          const float* agg, const float* Wt,
                                          const float* bt, float* outp,
                                          Smem* sm, int wave, int lane,
                                          int tid) {
  proj64(node, Wt, bt, sm->qp, sm, wave, lane, tid);

  for (int c = tid; c < 2 * ns * 64; c += 256) {
    int proj = c / (ns * 64);
    int r = (c >> 6) % ns;
    int n = c & 63;
    const float* w = Wt + (size_t)(proj + 1) * 4096;
    const float* src = (r == 0) ? node : (agg + (r - 1) * 64);
    float acc = bt[(proj + 1) * 64 + n];
#pragma unroll 8
    for (int k = 0; k < 64; ++k) acc += src[k] * w[k * 64 + n];
    sm->kvp[(proj * 3 + r) * 64 + n] = fmaxf(acc, 0.f);
  }
  __syncthreads();
  if (tid < ns) {
    float acc = 0.f;
#pragma unroll 8
    for (int k = 0; k < 64; ++k) acc += sm->qp[k] * sm->kvp[tid * 64 + k];
    sm->sc[tid] = acc * 0.125f;
  }
  __syncthreads();
  float mx = sm->sc[0];
  for (int i = 1; i < ns; ++i) mx = fmaxf(mx, sm->sc[i]);
  float e0 = __expf(sm->sc[0] - mx);
  float e1 = __expf(sm->sc[1] - mx);
  float e2 = (ns > 2) ? __expf(sm->sc[2] - mx) : 0.f;
  float rden = 1.f / (e0 + e1 + e2);
  if (tid < 64) {
    float yv = e0 * sm->kvp[(3 + 0) * 64 + tid] + e1 * sm->kvp[(3 + 1) * 64 + tid];
    if (ns > 2) yv += e2 * sm->kvp[(3 + 2) * 64 + tid];
    sm->y[tid] = yv * rden;
  }
  __syncthreads();
  float part = 0.f;
  const float* wp = Wt + 3 * 4096 + wave * 16 * 64 + lane;
#pragma unroll
  for (int kk = 0; kk < 16; ++kk) part += sm->y[wave * 16 + kk] * wp[kk * 64];
  sm->pp[wave * 64 + lane] = part;
  __syncthreads();
  if (tid < 64) {
    float v = sm->pp[tid] + sm->pp[64 + tid] + sm->pp[128 + tid] +
              sm->pp[192 + tid] + bt[192 + tid];
    outp[tid] = fmaxf(v, 0.f);
  }
  __syncthreads();
}

// ---- one block per (tower, batch): block-uniform branching only ------------
__global__ __launch_bounds__(256) void fused_towers(
    const int* __restrict__ uids, const int* __restrict__ qids,
    const int* __restrict__ mids, const int* __restrict__ u_movies,
    const int* __restrict__ m_querys, const int* __restrict__ m_users,
    const int* __restrict__ q_movies, const float* __restrict__ user_t,
    const float* __restrict__ item_t, const float* __restrict__ query_t,
    const float* __restrict__ gatW, const float* __restrict__ gatB,
    const float* __restrict__ semW, const float* __restrict__ semB,
    const bf16* __restrict__ wfrag, float* __restrict__ out) {
  __shared__ float node[64];
  __shared__ float agg[2][64];
  __shared__ Smem sm;

  int B = gridDim.x / 3;
  int tower = blockIdx.x / B;   // 0:U 1:M 2:Q (block-uniform)
  int b = blockIdx.x - tower * B;
  int tid = threadIdx.x;
  int lane = tid & 63;
  int wave = tid >> 6;

  // node row for this tower
  if (tid < 64) {
    int id = (tower == 0) ? uids[b] : (tower == 1 ? mids[b] : qids[b]);
    const float* tab = (tower == 0) ? user_t : (tower == 1 ? item_t : query_t);
    node[tid] = tab[(size_t)id * 64 + tid];
  }
  __syncthreads();

  float* outb = out + (size_t)b * 192 + tower * 64;

  if (tower == 0) {
    gat_layer(b, u_movies, item_t, gatW, gatB, wfrag, node, agg[0], &sm,
              wave, lane, tid);
    sem_layer(2, node, agg[0], semW, semB, outb, &sm, wave, lane, tid);
  } else if (tower == 1) {
    gat_layer(b, m_querys, query_t, gatW + 4 * 4096, gatB + 256, wfrag + 8192,
              node, agg[0], &sm, wave, lane, tid);
    gat_layer(b, m_users, user_t, gatW + 4 * 4096, gatB + 256, wfrag + 8192,
              node, agg[1], &sm, wave, lane, tid);
    sem_layer(3, node, agg[0], semW + 4 * 4096, semB + 256, outb, &sm,
              wave, lane, tid);
  } else {
    gat_layer(b, q_movies, item_t, gatW + 8 * 4096, gatB + 512, wfrag + 16384,
              node, agg[0], &sm, wave, lane, tid);
    sem_layer(2, node, agg[0], semW + 8 * 4096, semB + 512, outb, &sm,
              wave, lane, tid);
  }
}

extern "C" void kernel_launch(void* const* d_in, const int* in_sizes, int n_in,
                              void* d_out, int out_size, void* d_ws, size_t ws_size,
                              hipStream_t stream) {
  const int* uids = (const int*)d_in[0];
  const int* qids = (const int*)d_in[1];
  const int* mids = (const int*)d_in[2];
  const int* u_movies = (const int*)d_in[3];
  const int* m_querys = (const int*)d_in[4];
  const int* m_users = (const int*)d_in[5];
  const int* q_movies = (const int*)d_in[6];
  const float* user_t = (const float*)d_in[7];
  const float* item_t = (const float*)d_in[8];
  const float* query_t = (const float*)d_in[9];
  const float* gatW = (const float*)d_in[10];
  const float* gatB = (const float*)d_in[11];
  const float* semW = (const float*)d_in[12];
  const float* semB = (const float*)d_in[13];
  float* out = (float*)d_out;
  bf16* wfrag = (bf16*)d_ws; // 6*4096*2 = 48 KiB

  int B = in_sizes[0];
  shuffle_w<<<12, 256, 0, stream>>>(gatW, wfrag);
  fused_towers<<<3 * B, 256, 0, stream>>>(uids, qids, mids, u_movies, m_querys,
                                          m_users, q_movies, user_t, item_t,
                                          query_t, gatW, gatB, semW, semB,
                                          wfrag, out);
}

// Round 10
// 756.735 us; speedup vs baseline: 1.3932x; 1.3932x over previous
//
#include <hip/hip_runtime.h>

typedef __bf16 bf16;
typedef __bf16 bf16x8 __attribute__((ext_vector_type(8)));
typedef float f32x4 __attribute__((ext_vector_type(4)));

#define S_NB 50

// ---------------- weight pre-shuffle: f32 -> bf16 MFMA B-fragment layout ----
__global__ __launch_bounds__(256) void shuffle_w(const float* __restrict__ gatW,
                                                 bf16* __restrict__ ws) {
  int tid = blockIdx.x * 256 + threadIdx.x;
  if (tid >= 6 * 512) return;
  int mat = tid >> 9;
  int rem = tid & 511;
  int ks = rem >> 8;
  int nt = (rem >> 6) & 3;
  int lane = rem & 63;
  int t = mat >> 1, p = (mat & 1) + 1;
  const float* src = gatW + (size_t)(t * 4 + p) * 4096;
  int n = nt * 16 + (lane & 15);
  int kb = ks * 32 + (lane >> 4) * 8;
  bf16x8 v;
#pragma unroll
  for (int e = 0; e < 8; ++e) v[e] = (bf16)src[(kb + e) * 64 + n];
  *reinterpret_cast<bf16x8*>(ws + mat * 4096 + ((ks * 4 + nt) * 64 + lane) * 8) = v;
}

// ---------------- 2-batch fused layers (round-5 math, j=0,1 arrayed) --------
struct Smem {
  float qp[128];   // [j][64]
  float sc[128];
  float eb[128];
  float yp[512];   // [j][4][64]
  float y[128];
  float pp[512];   // [j][4][64]
  float kvp[768];  // [j][6][64]
};

__device__ __forceinline__ void proj64x2(const float* src, const float* W,
                                         const float* bias, float* dst,
                                         Smem* sm, int wave, int lane, int tid) {
  float p0 = 0.f, p1 = 0.f;
  const float* wp = W + wave * 16 * 64 + lane;
  const float* s0 = src + wave * 16;
  const float* s1 = src + 64 + wave * 16;
#pragma unroll
  for (int kk = 0; kk < 16; ++kk) {
    float w = wp[kk * 64];
    p0 += s0[kk] * w;
    p1 += s1[kk] * w;
  }
  sm->pp[wave * 64 + lane] = p0;
  sm->pp[256 + wave * 64 + lane] = p1;
  __syncthreads();
  if (tid < 64) {
    float bi = bias[tid];
    float v0 = sm->pp[tid] + sm->pp[64 + tid] + sm->pp[128 + tid] +
               sm->pp[192 + tid] + bi;
    float v1 = sm->pp[256 + tid] + sm->pp[320 + tid] + sm->pp[384 + tid] +
               sm->pp[448 + tid] + bi;
    dst[tid] = fmaxf(v0, 0.f);
    dst[64 + tid] = fmaxf(v1, 0.f);
  }
  __syncthreads();
}

__device__ __forceinline__ void gat_layer2(
    int b0, int b1, const int* idx, const float* table, const float* Wt,
    const float* bt, const bf16* frags, const float* node, float* aggdst,
    Smem* sm, int wave, int lane, int tid) {
  int c15 = lane & 15;
  int g = lane >> 4;
  int arow = wave * 16 + c15;

  // A fragments for both batches (rows 50..63 -> id 0 = zero row)
  bf16x8 a0[2], a1[2];
#pragma unroll
  for (int j = 0; j < 2; ++j) {
    int bj = j ? b1 : b0;
    int id = (arow < S_NB) ? idx[bj * S_NB + arow] : 0;
    const float* rowp = table + (size_t)id * 64;
    float4 f0 = *reinterpret_cast<const float4*>(rowp + g * 8);
    float4 f1 = *reinterpret_cast<const float4*>(rowp + g * 8 + 4);
    float4 f2 = *reinterpret_cast<const float4*>(rowp + 32 + g * 8);
    float4 f3 = *reinterpret_cast<const float4*>(rowp + 32 + g * 8 + 4);
    a0[j][0] = (bf16)f0.x; a0[j][1] = (bf16)f0.y; a0[j][2] = (bf16)f0.z; a0[j][3] = (bf16)f0.w;
    a0[j][4] = (bf16)f1.x; a0[j][5] = (bf16)f1.y; a0[j][6] = (bf16)f1.z; a0[j][7] = (bf16)f1.w;
    a1[j][0] = (bf16)f2.x; a1[j][1] = (bf16)f2.y; a1[j][2] = (bf16)f2.z; a1[j][3] = (bf16)f2.w;
    a1[j][4] = (bf16)f3.x; a1[j][5] = (bf16)f3.y; a1[j][6] = (bf16)f3.z; a1[j][7] = (bf16)f3.w;
  }

  // qp = relu(node @ W0 + b0) for both batches
  proj64x2(node, Wt, bt, sm->qp, sm, wave, lane, tid);

  // K projection via MFMA (weights loaded once, used for both batches)
  f32x4 kacc[2][4];
#pragma unroll
  for (int j = 0; j < 2; ++j)
#pragma unroll
    for (int nt = 0; nt < 4; ++nt) kacc[j][nt] = f32x4{0.f, 0.f, 0.f, 0.f};
  const bf16* fk = frags;
#pragma unroll
  for (int nt = 0; nt < 4; ++nt) {
#pragma unroll
    for (int ks = 0; ks < 2; ++ks) {
      bf16x8 bkf = *reinterpret_cast<const bf16x8*>(fk + ((ks * 4 + nt) * 64 + lane) * 8);
#pragma unroll
      for (int j = 0; j < 2; ++j) {
        bf16x8 a = ks ? a1[j] : a0[j];
        kacc[j][nt] = __builtin_amdgcn_mfma_f32_16x16x32_bf16(a, bkf, kacc[j][nt], 0, 0, 0);
      }
    }
  }

  // scores[row] = dot(qp, relu(kacc + kb));  row = wave*16 + g*4 + e
  float s0[4] = {0.f, 0.f, 0.f, 0.f}, s1[4] = {0.f, 0.f, 0.f, 0.f};
#pragma unroll
  for (int nt = 0; nt < 4; ++nt) {
    float kb = bt[64 + nt * 16 + c15];
    float qv0 = sm->qp[nt * 16 + c15];
    float qv1 = sm->qp[64 + nt * 16 + c15];
#pragma unroll
    for (int e = 0; e < 4; ++e) {
      s0[e] += fmaxf(kacc[0][nt][e] + kb, 0.f) * qv0;
      s1[e] += fmaxf(kacc[1][nt][e] + kb, 0.f) * qv1;
    }
  }
#pragma unroll
  for (int m = 1; m < 16; m <<= 1) {
#pragma unroll
    for (int e = 0; e < 4; ++e) {
      s0[e] += __shfl_xor(s0[e], m, 64);
      s1[e] += __shfl_xor(s1[e], m, 64);
    }
  }
  int rbase = wave * 16 + g * 4;
  if (c15 == 0) {
#pragma unroll
    for (int e = 0; e < 4; ++e) {
      sm->sc[rbase + e] = s0[e];
      sm->sc[64 + rbase + e] = s1[e];
    }
  }
  __syncthreads();

  // softmax over 50 (scale 1/8 folded into exp), interleaved j chains
  float mx0 = -1e30f, mx1 = -1e30f;
  for (int i = 0; i < S_NB; ++i) {
    mx0 = fmaxf(mx0, sm->sc[i]);
    mx1 = fmaxf(mx1, sm->sc[64 + i]);
  }
  if (tid < 64) {
    sm->eb[tid] = (tid < S_NB) ? __expf((sm->sc[tid] - mx0) * 0.125f) : 0.f;
    sm->eb[64 + tid] = (tid < S_NB) ? __expf((sm->sc[64 + tid] - mx1) * 0.125f) : 0.f;
  }
  __syncthreads();
  float den0 = 0.f, den1 = 0.f;
  for (int i = 0; i < S_NB; ++i) {
    den0 += sm->eb[i];
    den1 += sm->eb[64 + i];
  }
  float rden0 = 1.f / den0, rden1 = 1.f / den1;

  // V projection (after softmax: kacc and vacc never both live) + PV
  f32x4 vacc[2][4];
#pragma unroll
  for (int j = 0; j < 2; ++j)
#pragma unroll
    for (int nt = 0; nt < 4; ++nt) vacc[j][nt] = f32x4{0.f, 0.f, 0.f, 0.f};
  const bf16* fv = frags + 4096;
#pragma unroll
  for (int nt = 0; nt < 4; ++nt) {
#pragma unroll
    for (int ks = 0; ks < 2; ++ks) {
      bf16x8 bvf = *reinterpret_cast<const bf16x8*>(fv + ((ks * 4 + nt) * 64 + lane) * 8);
#pragma unroll
      for (int j = 0; j < 2; ++j) {
        bf16x8 a = ks ? a1[j] : a0[j];
        vacc[j][nt] = __builtin_amdgcn_mfma_f32_16x16x32_bf16(a, bvf, vacc[j][nt], 0, 0, 0);
      }
    }
  }
  float ew0[4], ew1[4];
#pragma unroll
  for (int e = 0; e < 4; ++e) {
    ew0[e] = sm->eb[rbase + e];
    ew1[e] = sm->eb[64 + rbase + e];
  }
#pragma unroll
  for (int nt = 0; nt < 4; ++nt) {
    float vb = bt[128 + nt * 16 + c15];
    float p0 = ew0[0] * fmaxf(vacc[0][nt][0] + vb, 0.f) +
               ew0[1] * fmaxf(vacc[0][nt][1] + vb, 0.f) +
               ew0[2] * fmaxf(vacc[0][nt][2] + vb, 0.f) +
               ew0[3] * fmaxf(vacc[0][nt][3] + vb, 0.f);
    float p1 = ew1[0] * fmaxf(vacc[1][nt][0] + vb, 0.f) +
               ew1[1] * fmaxf(vacc[1][nt][1] + vb, 0.f) +
               ew1[2] * fmaxf(vacc[1][nt][2] + vb, 0.f) +
               ew1[3] * fmaxf(vacc[1][nt][3] + vb, 0.f);
    p0 += __shfl_xor(p0, 16, 64);
    p0 += __shfl_xor(p0, 32, 64);
    p1 += __shfl_xor(p1, 16, 64);
    p1 += __shfl_xor(p1, 32, 64);
    if (lane < 16) {
      sm->yp[wave * 64 + nt * 16 + lane] = p0;
      sm->yp[256 + wave * 64 + nt * 16 + lane] = p1;
    }
  }
  __syncthreads();
  if (tid < 64) {
    sm->y[tid] = (sm->yp[tid] + sm->yp[64 + tid] + sm->yp[128 + tid] +
                  sm->yp[192 + tid]) * rden0;
    sm->y[64 + tid] = (sm->yp[256 + tid] + sm->yp[320 + tid] + sm->yp[384 + tid] +
                       sm->yp[448 + tid]) * rden1;
  }
  __syncthreads();

  // agg = relu(y @ W3 + b3)
  proj64x2(sm->y, Wt + 3 * 4096, bt + 192, aggdst, sm, wave, lane, tid);
}

__device__ __forceinline__ void sem_layer2(
    int ns, const float* node, const float* aggbuf, const float* Wt,
    const float* bt, float* out0, float* out1, Smem* sm, int wave, int lane,
    int tid) {
  proj64x2(node, Wt, bt, sm->qp, sm, wave, lane, tid);

  // kp/vp rows: cells over (proj, row, col); weight loads shared across j
  for (int cc = tid; cc < 2 * ns * 64; cc += 256) {
    int proj = cc / (ns * 64);
    int r = (cc >> 6) % ns;
    int n = cc & 63;
    const float* w = Wt + (size_t)(proj + 1) * 4096;
    const float* sA = (r == 0) ? node : (aggbuf + (r - 1) * 128);
    const float* sB = sA + 64;
    float acc0 = bt[(proj + 1) * 64 + n];
    float acc1 = acc0;
#pragma unroll 8
    for (int k = 0; k < 64; ++k) {
      float wv = w[k * 64 + n];
      acc0 += sA[k] * wv;
      acc1 += sB[k] * wv;
    }
    sm->kvp[(proj * 3 + r) * 64 + n] = fmaxf(acc0, 0.f);
    sm->kvp[384 + (proj * 3 + r) * 64 + n] = fmaxf(acc1, 0.f);
  }
  __syncthreads();
  if (tid < ns) {
    float acc0 = 0.f, acc1 = 0.f;
#pragma unroll 8
    for (int k = 0; k < 64; ++k) {
      acc0 += sm->qp[k] * sm->kvp[tid * 64 + k];
      acc1 += sm->qp[64 + k] * sm->kvp[384 + tid * 64 + k];
    }
    sm->sc[tid] = acc0 * 0.125f;
    sm->sc[64 + tid] = acc1 * 0.125f;
  }
  __syncthreads();
  // softmax over ns (redundant per thread), both batches
  float mx0 = sm->sc[0], mx1 = sm->sc[64];
  for (int i = 1; i < ns; ++i) {
    mx0 = fmaxf(mx0, sm->sc[i]);
    mx1 = fmaxf(mx1, sm->sc[64 + i]);
  }
  float e00 = __expf(sm->sc[0] - mx0), e01 = __expf(sm->sc[1] - mx0);
  float e02 = (ns > 2) ? __expf(sm->sc[2] - mx0) : 0.f;
  float r0 = 1.f / (e00 + e01 + e02);
  float e10 = __expf(sm->sc[64] - mx1), e11 = __expf(sm->sc[65] - mx1);
  float e12 = (ns > 2) ? __expf(sm->sc[66] - mx1) : 0.f;
  float r1 = 1.f / (e10 + e11 + e12);
  if (tid < 64) {
    float y0 = e00 * sm->kvp[192 + tid] + e01 * sm->kvp[256 + tid];
    if (ns > 2) y0 += e02 * sm->kvp[320 + tid];
    sm->y[tid] = y0 * r0;
    float y1 = e10 * sm->kvp[576 + tid] + e11 * sm->kvp[640 + tid];
    if (ns > 2) y1 += e12 * sm->kvp[704 + tid];
    sm->y[64 + tid] = y1 * r1;
  }
  __syncthreads();
  // out = relu(y @ W3 + b3) -> global f32, both batches
  float p0 = 0.f, p1 = 0.f;
  const float* wp = Wt + 3 * 4096 + wave * 16 * 64 + lane;
#pragma unroll
  for (int kk = 0; kk < 16; ++kk) {
    float w = wp[kk * 64];
    p0 += sm->y[wave * 16 + kk] * w;
    p1 += sm->y[64 + wave * 16 + kk] * w;
  }
  sm->pp[wave * 64 + lane] = p0;
  sm->pp[256 + wave * 64 + lane] = p1;
  __syncthreads();
  if (tid < 64) {
    float bi = bt[192 + tid];
    out0[tid] = fmaxf(sm->pp[tid] + sm->pp[64 + tid] + sm->pp[128 + tid] +
                      sm->pp[192 + tid] + bi, 0.f);
    out1[tid] = fmaxf(sm->pp[256 + tid] + sm->pp[320 + tid] + sm->pp[384 + tid] +
                      sm->pp[448 + tid] + bi, 0.f);
  }
  __syncthreads();
}

// ---- one block per (tower, batch-pair): block-uniform branching only -------
__global__ __launch_bounds__(256) void fused_towers(
    const int* __restrict__ uids, const int* __restrict__ qids,
    const int* __restrict__ mids, const int* __restrict__ u_movies,
    const int* __restrict__ m_querys, const int* __restrict__ m_users,
    const int* __restrict__ q_movies, const float* __restrict__ user_t,
    const float* __restrict__ item_t, const float* __restrict__ query_t,
    const float* __restrict__ gatW, const float* __restrict__ gatB,
    const float* __restrict__ semW, const float* __restrict__ semB,
    const bf16* __restrict__ wfrag, float* __restrict__ out) {
  __shared__ float node[128];   // [j][64]
  __shared__ float aggb[256];   // [i][j][64]
  __shared__ Smem sm;

  int nbp = gridDim.x / 3;
  int tower = blockIdx.x / nbp;  // 0:U 1:M 2:Q (block-uniform)
  int pair = blockIdx.x - tower * nbp;
  int b0 = pair * 2;
  int b1 = b0 + 1;  // B = 16384 is even
  int tid = threadIdx.x;
  int lane = tid & 63;
  int wave = tid >> 6;

  if (tid < 128) {
    int j = tid >> 6, n = tid & 63;
    int bj = j ? b1 : b0;
    int id = (tower == 0) ? uids[bj] : (tower == 1 ? mids[bj] : qids[bj]);
    const float* tab = (tower == 0) ? user_t : (tower == 1 ? item_t : query_t);
    node[j * 64 + n] = tab[(size_t)id * 64 + n];
  }
  __syncthreads();

  float* out0 = out + (size_t)b0 * 192 + tower * 64;
  float* out1 = out + (size_t)b1 * 192 + tower * 64;

  if (tower == 0) {
    gat_layer2(b0, b1, u_movies, item_t, gatW, gatB, wfrag, node, aggb, &sm,
               wave, lane, tid);
    sem_layer2(2, node, aggb, semW, semB, out0, out1, &sm, wave, lane, tid);
  } else if (tower == 1) {
    gat_layer2(b0, b1, m_querys, query_t, gatW + 4 * 4096, gatB + 256,
               wfrag + 8192, node, aggb, &sm, wave, lane, tid);
    gat_layer2(b0, b1, m_users, user_t, gatW + 4 * 4096, gatB + 256,
               wfrag + 8192, node, aggb + 128, &sm, wave, lane, tid);
    sem_layer2(3, node, aggb, semW + 4 * 4096, semB + 256, out0, out1, &sm,
               wave, lane, tid);
  } else {
    gat_layer2(b0, b1, q_movies, item_t, gatW + 8 * 4096, gatB + 512,
               wfrag + 16384, node, aggb, &sm, wave, lane, tid);
    sem_layer2(2, node, aggb, semW + 8 * 4096, semB + 512, out0, out1, &sm,
               wave, lane, tid);
  }
}

extern "C" void kernel_launch(void* const* d_in, const int* in_sizes, int n_in,
                              void* d_out, int out_size, void* d_ws, size_t ws_size,
                              hipStream_t stream) {
  const int* uids = (const int*)d_in[0];
  const int* qids = (const int*)d_in[1];
  const int* mids = (const int*)d_in[2];
  const int* u_movies = (const int*)d_in[3];
  const int* m_querys = (const int*)d_in[4];
  const int* m_users = (const int*)d_in[5];
  const int* q_movies = (const int*)d_in[6];
  const float* user_t = (const float*)d_in[7];
  const float* item_t = (const float*)d_in[8];
  const float* query_t = (const float*)d_in[9];
  const float* gatW = (const float*)d_in[10];
  const float* gatB = (const float*)d_in[11];
  const float* semW = (const float*)d_in[12];
  const float* semB = (const float*)d_in[13];
  float* out = (float*)d_out;
  bf16* wfrag = (bf16*)d_ws; // 6*4096*2 = 48 KiB

  int B = in_sizes[0];
  int nbp = B / 2;  // B = 16384 even
  shuffle_w<<<12, 256, 0, stream>>>(gatW, wfrag);
  fused_towers<<<3 * nbp, 256, 0, stream>>>(uids, qids, mids, u_movies,
                                            m_querys, m_users, q_movies,
                                            user_t, item_t, query_t, gatW,
                                            gatB, semW, semB, wfrag, out);
}

// Round 11
// 694.529 us; speedup vs baseline: 1.5180x; 1.0896x over previous
//
#include <hip/hip_runtime.h>

typedef __bf16 bf16;
typedef __bf16 bf16x8 __attribute__((ext_vector_type(8)));
typedef float f32x4 __attribute__((ext_vector_type(4)));

#define S_NB 50

// ---------------- weight pre-shuffle: f32 -> bf16 MFMA B-fragment layout ----
__global__ __launch_bounds__(256) void shuffle_w(const float* __restrict__ gatW,
                                                 bf16* __restrict__ ws) {
  int tid = blockIdx.x * 256 + threadIdx.x;
  if (tid >= 6 * 512) return;
  int mat = tid >> 9;
  int rem = tid & 511;
  int ks = rem >> 8;
  int nt = (rem >> 6) & 3;
  int lane = rem & 63;
  int t = mat >> 1, p = (mat & 1) + 1;
  const float* src = gatW + (size_t)(t * 4 + p) * 4096;
  int n = nt * 16 + (lane & 15);
  int kb = ks * 32 + (lane >> 4) * 8;
  bf16x8 v;
#pragma unroll
  for (int e = 0; e < 8; ++e) v[e] = (bf16)src[(kb + e) * 64 + n];
  *reinterpret_cast<bf16x8*>(ws + mat * 4096 + ((ks * 4 + nt) * 64 + lane) * 8) = v;
}

// ---------------- 4-batch fused layers (round-10 math, j=0..3 arrayed) ------
struct Smem {
  float node[4][64];
  float qp[4][64];
  float sc[4][64];
  float eb[4][64];
  float yp[4][4][64];  // [j][wave][col]
  float y[4][64];
  float kvp[4][6][64]; // [j][proj*3+r][col]
  float aggb[2][4][64];
};

__device__ __forceinline__ void gat_layer4(
    int b0, const int* idx, const float* table, const float* Wt,
    const float* bt, const bf16* frags, float (*aggdst)[64], Smem* sm,
    int wave, int lane, int tid) {
  int c15 = lane & 15;
  int g = lane >> 4;
  int arow = wave * 16 + c15;
  int rbase = wave * 16 + g * 4;

  // A fragments: 4 batches x 2 k-halves (rows 50..63 -> id 0 = zero row)
  bf16x8 af0[4], af1[4];
#pragma unroll
  for (int j = 0; j < 4; ++j) {
    int id = (arow < S_NB) ? idx[(b0 + j) * S_NB + arow] : 0;
    const float* rowp = table + (size_t)id * 64;
    float4 f0 = *reinterpret_cast<const float4*>(rowp + g * 8);
    float4 f1 = *reinterpret_cast<const float4*>(rowp + g * 8 + 4);
    float4 f2 = *reinterpret_cast<const float4*>(rowp + 32 + g * 8);
    float4 f3 = *reinterpret_cast<const float4*>(rowp + 32 + g * 8 + 4);
    af0[j][0] = (bf16)f0.x; af0[j][1] = (bf16)f0.y; af0[j][2] = (bf16)f0.z; af0[j][3] = (bf16)f0.w;
    af0[j][4] = (bf16)f1.x; af0[j][5] = (bf16)f1.y; af0[j][6] = (bf16)f1.z; af0[j][7] = (bf16)f1.w;
    af1[j][0] = (bf16)f2.x; af1[j][1] = (bf16)f2.y; af1[j][2] = (bf16)f2.z; af1[j][3] = (bf16)f2.w;
    af1[j][4] = (bf16)f3.x; af1[j][5] = (bf16)f3.y; af1[j][6] = (bf16)f3.z; af1[j][7] = (bf16)f3.w;
  }

  // Phase B: qp col-parallel (j = wave, col = lane); 16-k chunk partials
  {
    const float* src = sm->node[wave];
    float a0 = 0.f, a1 = 0.f, a2 = 0.f, a3 = 0.f;
#pragma unroll 4
    for (int kk = 0; kk < 16; ++kk) {
      a0 += src[kk] * Wt[kk * 64 + lane];
      a1 += src[16 + kk] * Wt[(16 + kk) * 64 + lane];
      a2 += src[32 + kk] * Wt[(32 + kk) * 64 + lane];
      a3 += src[48 + kk] * Wt[(48 + kk) * 64 + lane];
    }
    sm->qp[wave][lane] = fmaxf((((a0 + a1) + a2) + a3) + bt[lane], 0.f);
  }
  __syncthreads();  // (1) qp visible

  // Phase C: K-proj MFMA (B-frags shared across 4 batches) + folded scores
  float s[4][4];
#pragma unroll
  for (int j = 0; j < 4; ++j)
#pragma unroll
    for (int e = 0; e < 4; ++e) s[j][e] = 0.f;
#pragma unroll
  for (int nt = 0; nt < 4; ++nt) {
    bf16x8 bk0 = *reinterpret_cast<const bf16x8*>(frags + ((0 * 4 + nt) * 64 + lane) * 8);
    bf16x8 bk1 = *reinterpret_cast<const bf16x8*>(frags + ((1 * 4 + nt) * 64 + lane) * 8);
    float kb = bt[64 + nt * 16 + c15];
#pragma unroll
    for (int j = 0; j < 4; ++j) {
      f32x4 acc = {0.f, 0.f, 0.f, 0.f};
      acc = __builtin_amdgcn_mfma_f32_16x16x32_bf16(af0[j], bk0, acc, 0, 0, 0);
      acc = __builtin_amdgcn_mfma_f32_16x16x32_bf16(af1[j], bk1, acc, 0, 0, 0);
      float qv = sm->qp[j][nt * 16 + c15];
#pragma unroll
      for (int e = 0; e < 4; ++e) s[j][e] += fmaxf(acc[e] + kb, 0.f) * qv;
    }
  }
#pragma unroll
  for (int m = 1; m < 16; m <<= 1)
#pragma unroll
    for (int j = 0; j < 4; ++j)
#pragma unroll
      for (int e = 0; e < 4; ++e) s[j][e] += __shfl_xor(s[j][e], m, 64);
  if (c15 == 0) {
#pragma unroll
    for (int j = 0; j < 4; ++j)
#pragma unroll
      for (int e = 0; e < 4; ++e) sm->sc[j][rbase + e] = s[j][e];
  }
  __syncthreads();  // (2) scores visible

  // Phase D: softmax, one chain per wave (serial order matches round 10)
  {
    int j = wave;
    float mx = -1e30f;
    for (int i = 0; i < S_NB; ++i) mx = fmaxf(mx, sm->sc[j][i]);
    sm->eb[j][lane] = (lane < S_NB) ? __expf((sm->sc[j][lane] - mx) * 0.125f) : 0.f;
  }
  __syncthreads();  // (3) eb visible
  float rden;
  {
    int j = wave;
    float den = 0.f;
    for (int i = 0; i < S_NB; ++i) den += sm->eb[j][i];
    rden = 1.f / den;
  }

  // Phase E: V-proj MFMA + folded PV
  float ew[4][4];
#pragma unroll
  for (int j = 0; j < 4; ++j)
#pragma unroll
    for (int e = 0; e < 4; ++e) ew[j][e] = sm->eb[j][rbase + e];
#pragma unroll
  for (int nt = 0; nt < 4; ++nt) {
    bf16x8 bv0 = *reinterpret_cast<const bf16x8*>(frags + 4096 + ((0 * 4 + nt) * 64 + lane) * 8);
    bf16x8 bv1 = *reinterpret_cast<const bf16x8*>(frags + 4096 + ((1 * 4 + nt) * 64 + lane) * 8);
    float vb = bt[128 + nt * 16 + c15];
#pragma unroll
    for (int j = 0; j < 4; ++j) {
      f32x4 acc = {0.f, 0.f, 0.f, 0.f};
      acc = __builtin_amdgcn_mfma_f32_16x16x32_bf16(af0[j], bv0, acc, 0, 0, 0);
      acc = __builtin_amdgcn_mfma_f32_16x16x32_bf16(af1[j], bv1, acc, 0, 0, 0);
      float p = ew[j][0] * fmaxf(acc[0] + vb, 0.f) +
                ew[j][1] * fmaxf(acc[1] + vb, 0.f) +
                ew[j][2] * fmaxf(acc[2] + vb, 0.f) +
                ew[j][3] * fmaxf(acc[3] + vb, 0.f);
      p += __shfl_xor(p, 16, 64);
      p += __shfl_xor(p, 32, 64);
      if (lane < 16) sm->yp[j][wave][nt * 16 + lane] = p;
    }
  }
  __syncthreads();  // (4) yp visible

  // Phase F: y reduce, col-parallel (j = wave; rden held by this wave)
  sm->y[wave][lane] = (((sm->yp[wave][0][lane] + sm->yp[wave][1][lane]) +
                        sm->yp[wave][2][lane]) + sm->yp[wave][3][lane]) * rden;
  __syncthreads();  // (5) y visible

  // Phase G: agg = relu(y @ W3 + b3), col-parallel
  {
    const float* W3 = Wt + 3 * 4096;
    const float* src = sm->y[wave];
    float a0 = 0.f, a1 = 0.f, a2 = 0.f, a3 = 0.f;
#pragma unroll 4
    for (int kk = 0; kk < 16; ++kk) {
      a0 += src[kk] * W3[kk * 64 + lane];
      a1 += src[16 + kk] * W3[(16 + kk) * 64 + lane];
      a2 += src[32 + kk] * W3[(32 + kk) * 64 + lane];
      a3 += src[48 + kk] * W3[(48 + kk) * 64 + lane];
    }
    aggdst[wave][lane] = fmaxf((((a0 + a1) + a2) + a3) + bt[192 + lane], 0.f);
  }
  __syncthreads();  // (6) agg visible
}

__device__ __forceinline__ void sem_layer4(
    int ns, int b0, int toff, const float* Wt, const float* bt, float* out,
    Smem* sm, int wave, int lane, int tid) {
  // qp col-parallel (j = wave)
  {
    const float* src = sm->node[wave];
    float a0 = 0.f, a1 = 0.f, a2 = 0.f, a3 = 0.f;
#pragma unroll 4
    for (int kk = 0; kk < 16; ++kk) {
      a0 += src[kk] * Wt[kk * 64 + lane];
      a1 += src[16 + kk] * Wt[(16 + kk) * 64 + lane];
      a2 += src[32 + kk] * Wt[(32 + kk) * 64 + lane];
      a3 += src[48 + kk] * Wt[(48 + kk) * 64 + lane];
    }
    sm->qp[wave][lane] = fmaxf((((a0 + a1) + a2) + a3) + bt[lane], 0.f);
  }
  __syncthreads();  // (1)

  // kp/vp cells: (proj, r, n), 4 j accumulators share each weight load
  for (int cc = tid; cc < 2 * ns * 64; cc += 256) {
    int proj = cc / (ns * 64);
    int r = (cc >> 6) % ns;
    int n = cc & 63;
    const float* w = Wt + (size_t)(proj + 1) * 4096;
    const float* sN = (r == 0) ? &sm->node[0][0] : &sm->aggb[r - 1][0][0];
    float acc0 = bt[(proj + 1) * 64 + n];
    float acc1 = acc0, acc2 = acc0, acc3 = acc0;
#pragma unroll 8
    for (int k = 0; k < 64; ++k) {
      float wv = w[k * 64 + n];
      acc0 += sN[k] * wv;
      acc1 += sN[64 + k] * wv;
      acc2 += sN[128 + k] * wv;
      acc3 += sN[192 + k] * wv;
    }
    sm->kvp[0][proj * 3 + r][n] = fmaxf(acc0, 0.f);
    sm->kvp[1][proj * 3 + r][n] = fmaxf(acc1, 0.f);
    sm->kvp[2][proj * 3 + r][n] = fmaxf(acc2, 0.f);
    sm->kvp[3][proj * 3 + r][n] = fmaxf(acc3, 0.f);
  }
  __syncthreads();  // (2)

  // scores: thread (j, r)
  if (tid < 4 * ns) {
    int j = tid / ns, r = tid - (tid / ns) * ns;
    float acc = 0.f;
#pragma unroll 8
    for (int k = 0; k < 64; ++k) acc += sm->qp[j][k] * sm->kvp[j][r][k];
    sm->sc[j][r] = acc * 0.125f;
  }
  __syncthreads();  // (3)

  // softmax over ns + y, col-parallel (j = wave)
  {
    int j = wave;
    float mx = sm->sc[j][0];
    for (int i = 1; i < ns; ++i) mx = fmaxf(mx, sm->sc[j][i]);
    float e0 = __expf(sm->sc[j][0] - mx);
    float e1 = __expf(sm->sc[j][1] - mx);
    float e2 = (ns > 2) ? __expf(sm->sc[j][2] - mx) : 0.f;
    float rd = 1.f / (e0 + e1 + e2);
    float yv = e0 * sm->kvp[j][3][lane] + e1 * sm->kvp[j][4][lane];
    if (ns > 2) yv += e2 * sm->kvp[j][5][lane];
    sm->y[j][lane] = yv * rd;
  }
  __syncthreads();  // (4)

  // out = relu(y @ W3 + b3) -> global f32, col-parallel
  {
    const float* W3 = Wt + 3 * 4096;
    const float* src = sm->y[wave];
    float a0 = 0.f, a1 = 0.f, a2 = 0.f, a3 = 0.f;
#pragma unroll 4
    for (int kk = 0; kk < 16; ++kk) {
      a0 += src[kk] * W3[kk * 64 + lane];
      a1 += src[16 + kk] * W3[(16 + kk) * 64 + lane];
      a2 += src[32 + kk] * W3[(32 + kk) * 64 + lane];
      a3 += src[48 + kk] * W3[(48 + kk) * 64 + lane];
    }
    out[(size_t)(b0 + wave) * 192 + toff + lane] =
        fmaxf((((a0 + a1) + a2) + a3) + bt[192 + lane], 0.f);
  }
}

// ---- one block per (tower, batch-quad): block-uniform branching only -------
__global__ __launch_bounds__(256) void fused_towers(
    const int* __restrict__ uids, const int* __restrict__ qids,
    const int* __restrict__ mids, const int* __restrict__ u_movies,
    const int* __restrict__ m_querys, const int* __restrict__ m_users,
    const int* __restrict__ q_movies, const float* __restrict__ user_t,
    const float* __restrict__ item_t, const float* __restrict__ query_t,
    const float* __restrict__ gatW, const float* __restrict__ gatB,
    const float* __restrict__ semW, const float* __restrict__ semB,
    const bf16* __restrict__ wfrag, float* __restrict__ out) {
  __shared__ Smem sm;

  int nb4 = gridDim.x / 3;
  int tower = blockIdx.x / nb4;  // 0:U 1:M 2:Q (block-uniform)
  int quad = blockIdx.x - tower * nb4;
  int b0 = quad * 4;
  int tid = threadIdx.x;
  int lane = tid & 63;
  int wave = tid >> 6;

  // node rows: thread (j = wave, n = lane)
  {
    int bj = b0 + wave;
    int id = (tower == 0) ? uids[bj] : (tower == 1 ? mids[bj] : qids[bj]);
    const float* tab = (tower == 0) ? user_t : (tower == 1 ? item_t : query_t);
    sm.node[wave][lane] = tab[(size_t)id * 64 + lane];
  }
  __syncthreads();

  if (tower == 0) {
    gat_layer4(b0, u_movies, item_t, gatW, gatB, wfrag, sm.aggb[0], &sm,
               wave, lane, tid);
    sem_layer4(2, b0, 0, semW, semB, out, &sm, wave, lane, tid);
  } else if (tower == 1) {
    gat_layer4(b0, m_querys, query_t, gatW + 4 * 4096, gatB + 256,
               wfrag + 8192, sm.aggb[0], &sm, wave, lane, tid);
    gat_layer4(b0, m_users, user_t, gatW + 4 * 4096, gatB + 256,
               wfrag + 8192, sm.aggb[1], &sm, wave, lane, tid);
    sem_layer4(3, b0, 64, semW + 4 * 4096, semB + 256, out, &sm, wave, lane, tid);
  } else {
    gat_layer4(b0, q_movies, item_t, gatW + 8 * 4096, gatB + 512,
               wfrag + 16384, sm.aggb[0], &sm, wave, lane, tid);
    sem_layer4(2, b0, 128, semW + 8 * 4096, semB + 512, out, &sm, wave, lane, tid);
  }
}

extern "C" void kernel_launch(void* const* d_in, const int* in_sizes, int n_in,
                              void* d_out, int out_size, void* d_ws, size_t ws_size,
                              hipStream_t stream) {
  const int* uids = (const int*)d_in[0];
  const int* qids = (const int*)d_in[1];
  const int* mids = (const int*)d_in[2];
  const int* u_movies = (const int*)d_in[3];
  const int* m_querys = (const int*)d_in[4];
  const int* m_users = (const int*)d_in[5];
  const int* q_movies = (const int*)d_in[6];
  const float* user_t = (const float*)d_in[7];
  const float* item_t = (const float*)d_in[8];
  const float* query_t = (const float*)d_in[9];
  const float* gatW = (const float*)d_in[10];
  const float* gatB = (const float*)d_in[11];
  const float* semW = (const float*)d_in[12];
  const float* semB = (const float*)d_in[13];
  float* out = (float*)d_out;
  bf16* wfrag = (bf16*)d_ws; // 6*4096*2 = 48 KiB

  int B = in_sizes[0];
  int nb4 = B / 4;  // B = 16384, divisible by 4
  shuffle_w<<<12, 256, 0, stream>>>(gatW, wfrag);
  fused_towers<<<3 * nb4, 256, 0, stream>>>(uids, qids, mids, u_movies,
                                            m_querys, m_users, q_movies,
                                            user_t, item_t, query_t, gatW,
                                            gatB, semW, semB, wfrag, out);
}